// Round 13
// baseline (6413.122 us; speedup 1.0000x reference)
//
#include <hip/hip_runtime.h>
#include <hip/hip_bf16.h>
#include <math.h>

#define VDIM 128
#define HDIM 512
#define BATCH 512
#define RPB 4                  // batch rows per scan block
#define NBLK (BATCH / RPB)     // 128 scan blocks
#define NWORK 128              // persistent fnet worker blocks
#define NT 512
#define NWAVE 8
#define LN_EPS 1e-5f
#define PFQ 4                  // prefetched q-iterations (16 float4/thread)
#define FROWS 32               // fnet rows per tile
#define NGRP 16                // worker row groups (32 rows)
#define SBPG 8                 // scan blocks per worker row group

// ---------- float4 helpers ----------
__device__ __forceinline__ float4 f4zero() { return make_float4(0.f, 0.f, 0.f, 0.f); }
__device__ __forceinline__ float4 f4add(float4 a, float4 b) {
    return make_float4(a.x + b.x, a.y + b.y, a.z + b.z, a.w + b.w);
}
__device__ __forceinline__ float4 f4fma(float4 a, float s, float4 c) {
    return make_float4(fmaf(a.x, s, c.x), fmaf(a.y, s, c.y),
                       fmaf(a.z, s, c.z), fmaf(a.w, s, c.w));
}
__device__ __forceinline__ float4 f4scale(float4 a, float s) {
    return make_float4(a.x * s, a.y * s, a.z * s, a.w * s);
}
__device__ __forceinline__ float4 f4sub(float4 a, float4 b) {
    return make_float4(a.x - b.x, a.y - b.y, a.z - b.z, a.w - b.w);
}
__device__ __forceinline__ float f4get(float4 v, int r) {
    return r == 0 ? v.x : r == 1 ? v.y : r == 2 ? v.z : v.w;
}

struct Params {
    const float *u;
    const float *q_w1, *q_b1, *q_g1, *q_be1;
    const float *q_w2, *q_b2, *q_g2, *q_be2;
    const float *q_w3, *q_b3, *q_g3, *q_be3;
    const float *q_W, *q_bias, *q_marg;
    const float *f_w1, *f_b1, *f_g1, *f_be1;
    const float *f_w2, *f_b2, *f_g2, *f_be2;
    const float *f_w3, *f_b3, *f_g3, *f_be3;
    const float *f_w4, *f_b4, *J;
    const int *top_order, *pa_mask;
    int *wflag;
    float *V_out, *lp, *lf, *score, *vs, *loss;
};

// ---------------- shared-memory roles (union -> ~82KB -> 1 block/CU) -----
struct ScanS {
    float4 VT[VDIM];           // V^T: [col] -> 4 rows
    float4 VPT[VDIM];          // permuted layer-1 input
    float4 ATa[HDIM];          // permuted activations st(c)=(c&3)*(K/4)+(c>>2)
    float4 ATb[HDIM];
    float4 part[4][4][128];    // [j][ks][cb]  32KB
    float4 red2[NWAVE][2];     // fused-stat allreduce
    float4 redH[NWAVE];        // head / score allreduce
    int ord[VDIM];
    int emptyb[VDIM];          // precomputed empty-parent flags per step
};
struct WorkS {
    float Vt[VDIM * FROWS];    // 16KB [k][32]
    float A[HDIM * FROWS];     // 64KB [c][32]
    int ord[VDIM], invp[VDIM];
    float4 redA[NWAVE], redB[NWAVE];
};
union SMem { ScanS s; WorkS w; };

// ---- block-wide f4 allreduce, ONE sync ---------------------------------
__device__ __forceinline__ float4 allreduce4_1s(float4 v, float4 *red, int tid) {
#pragma unroll
    for (int off = 1; off < 64; off <<= 1) {
        v.x += __shfl_xor(v.x, off, 64);
        v.y += __shfl_xor(v.y, off, 64);
        v.z += __shfl_xor(v.z, off, 64);
        v.w += __shfl_xor(v.w, off, 64);
    }
    if ((tid & 63) == 0) red[tid >> 6] = v;
    __syncthreads();
    float4 s = red[0];
#pragma unroll
    for (int w = 1; w < NWAVE; ++w) s = f4add(s, red[w]);
    return s;   // no trailing sync
}

// ---- block-wide 2xf4 allreduce (fused mean/meansq), ONE sync -----------
__device__ __forceinline__ void allreduce2_1s(float4 &a, float4 &b,
                                              float4 (*red)[2], int tid) {
#pragma unroll
    for (int off = 1; off < 64; off <<= 1) {
        a.x += __shfl_xor(a.x, off, 64); a.y += __shfl_xor(a.y, off, 64);
        a.z += __shfl_xor(a.z, off, 64); a.w += __shfl_xor(a.w, off, 64);
        b.x += __shfl_xor(b.x, off, 64); b.y += __shfl_xor(b.y, off, 64);
        b.z += __shfl_xor(b.z, off, 64); b.w += __shfl_xor(b.w, off, 64);
    }
    if ((tid & 63) == 0) { red[tid >> 6][0] = a; red[tid >> 6][1] = b; }
    __syncthreads();
    float4 sa = red[0][0], sb = red[0][1];
#pragma unroll
    for (int w = 1; w < NWAVE; ++w) { sa = f4add(sa, red[w][0]); sb = f4add(sb, red[w][1]); }
    a = sa; b = sb;   // no trailing sync
}

__device__ __forceinline__ float block_reduce1(float v, float *red, int tid) {
#pragma unroll
    for (int off = 1; off < 64; off <<= 1) v += __shfl_xor(v, off, 64);
    if ((tid & 63) == 0) red[tid >> 6] = v;
    __syncthreads();
    float s = 0.f;
#pragma unroll
    for (int w = 0; w < NWAVE; ++w) s += red[w];
    __syncthreads();
    return s;
}

__device__ __forceinline__ void redpair(float4 &a, float4 &b,
                                        float4 *redA, float4 *redB, int tid) {
#pragma unroll
    for (int off = 1; off < 64; off <<= 1) {
        a.x += __shfl_xor(a.x, off, 64); a.y += __shfl_xor(a.y, off, 64);
        a.z += __shfl_xor(a.z, off, 64); a.w += __shfl_xor(a.w, off, 64);
        b.x += __shfl_xor(b.x, off, 64); b.y += __shfl_xor(b.y, off, 64);
        b.z += __shfl_xor(b.z, off, 64); b.w += __shfl_xor(b.w, off, 64);
    }
    int w = tid >> 6;
    if ((tid & 63) == 0) { redA[w] = a; redB[w] = b; }
    __syncthreads();
    int p = w ^ 1;
    a = f4add(redA[w], redA[p]);
    b = f4add(redB[w], redB[p]);
    __syncthreads();
}

// ---------------- scan GEMV + fused-stat LN + cross-layer prefetch ------
// pf[4*PFQ]: IN = this layer's first PFQ q-iterations of W (loaded by the
// previous layer's tail / prologue); OUT = next layer's first PFQ q's,
// issued BEFORE the partials barrier so they fly during sync/LN phases.
template <int K>
__device__ __forceinline__ void gemv_ln_scan(const float4 *__restrict__ inA,
                                             const float *__restrict__ W,
                                             const float *__restrict__ bias,
                                             const float *__restrict__ gam,
                                             const float *__restrict__ bet,
                                             float4 *__restrict__ outA,
                                             ScanS &S, int tid, int ks, int cq,
                                             int myc, float4 *pf,
                                             const float4 *__restrict__ pfNext) {
    constexpr int kc = K / 4;
    constexpr int q4 = kc / 4;
    constexpr int seg = K / 4;
    const float4 *Wp = (const float4 *)W + (size_t)(ks * kc) * (HDIM / 4) + cq;
    const float4 *ap = inA + ks * q4;
    float4 acc0 = f4zero(), acc1 = f4zero(), acc2 = f4zero(), acc3 = f4zero();
    // prefetched head of the loop (weights already in registers)
#pragma unroll
    for (int q = 0; q < PFQ; ++q) {
        float4 a0 = ap[q];
        float4 a1 = ap[q + seg];
        float4 a2 = ap[q + 2 * seg];
        float4 a3 = ap[q + 3 * seg];
        float4 w0 = pf[4 * q + 0];
        float4 w1 = pf[4 * q + 1];
        float4 w2 = pf[4 * q + 2];
        float4 w3 = pf[4 * q + 3];
        acc0 = f4fma(a0, w0.x, acc0); acc1 = f4fma(a0, w0.y, acc1);
        acc2 = f4fma(a0, w0.z, acc2); acc3 = f4fma(a0, w0.w, acc3);
        acc0 = f4fma(a1, w1.x, acc0); acc1 = f4fma(a1, w1.y, acc1);
        acc2 = f4fma(a1, w1.z, acc2); acc3 = f4fma(a1, w1.w, acc3);
        acc0 = f4fma(a2, w2.x, acc0); acc1 = f4fma(a2, w2.y, acc1);
        acc2 = f4fma(a2, w2.z, acc2); acc3 = f4fma(a2, w2.w, acc3);
        acc0 = f4fma(a3, w3.x, acc0); acc1 = f4fma(a3, w3.y, acc1);
        acc2 = f4fma(a3, w3.z, acc2); acc3 = f4fma(a3, w3.w, acc3);
    }
#pragma unroll 4
    for (int q = PFQ; q < q4; ++q) {
        float4 a0 = ap[q];                 // LDS b128 broadcast
        float4 a1 = ap[q + seg];
        float4 a2 = ap[q + 2 * seg];
        float4 a3 = ap[q + 3 * seg];
        float4 w0 = Wp[(size_t)(4 * q + 0) * (HDIM / 4)];   // 1KB/wave coalesced
        float4 w1 = Wp[(size_t)(4 * q + 1) * (HDIM / 4)];
        float4 w2 = Wp[(size_t)(4 * q + 2) * (HDIM / 4)];
        float4 w3 = Wp[(size_t)(4 * q + 3) * (HDIM / 4)];
        acc0 = f4fma(a0, w0.x, acc0); acc1 = f4fma(a0, w0.y, acc1);
        acc2 = f4fma(a0, w0.z, acc2); acc3 = f4fma(a0, w0.w, acc3);
        acc0 = f4fma(a1, w1.x, acc0); acc1 = f4fma(a1, w1.y, acc1);
        acc2 = f4fma(a1, w1.z, acc2); acc3 = f4fma(a1, w1.w, acc3);
        acc0 = f4fma(a2, w2.x, acc0); acc1 = f4fma(a2, w2.y, acc1);
        acc2 = f4fma(a2, w2.z, acc2); acc3 = f4fma(a2, w2.w, acc3);
        acc0 = f4fma(a3, w3.x, acc0); acc1 = f4fma(a3, w3.y, acc1);
        acc2 = f4fma(a3, w3.z, acc2); acc3 = f4fma(a3, w3.w, acc3);
    }
    // refill pf with NEXT layer's first PFQ q's — in flight across the
    // barrier/LN phases below (issued before the vmcnt-draining barrier).
#pragma unroll
    for (int q = 0; q < PFQ; ++q) {
        pf[4 * q + 0] = pfNext[(size_t)(4 * q + 0) * (HDIM / 4)];
        pf[4 * q + 1] = pfNext[(size_t)(4 * q + 1) * (HDIM / 4)];
        pf[4 * q + 2] = pfNext[(size_t)(4 * q + 2) * (HDIM / 4)];
        pf[4 * q + 3] = pfNext[(size_t)(4 * q + 3) * (HDIM / 4)];
    }
    S.part[0][ks][cq] = acc0;
    S.part[1][ks][cq] = acc1;
    S.part[2][ks][cq] = acc2;
    S.part[3][ks][cq] = acc3;
    __syncthreads();                                   // sync 1
    // combine: thread tid owns column myc = 4*cq + ks
    const int j = ks, cb = cq;
    float4 z = f4add(f4add(S.part[j][0][cb], S.part[j][1][cb]),
                     f4add(S.part[j][2][cb], S.part[j][3][cb]));
    float bc = bias[myc];
    z.x += bc; z.y += bc; z.z += bc; z.w += bc;
    // fused stats: one allreduce for (sum, sumsq); var = E[z^2] - m^2
    const float inv = 1.f / (float)HDIM;
    float4 s1 = z;
    float4 s2 = make_float4(z.x * z.x, z.y * z.y, z.z * z.z, z.w * z.w);
    allreduce2_1s(s1, s2, S.red2, tid);                // sync 2
    float4 m = f4scale(s1, inv);
    float4 e2 = f4scale(s2, inv);
    float4 var = make_float4(fmaxf(e2.x - m.x * m.x, 0.f),
                             fmaxf(e2.y - m.y * m.y, 0.f),
                             fmaxf(e2.z - m.z * m.z, 0.f),
                             fmaxf(e2.w - m.w * m.w, 0.f));
    float4 rs;
    rs.x = 1.f / sqrtf(var.x + LN_EPS);
    rs.y = 1.f / sqrtf(var.y + LN_EPS);
    rs.z = 1.f / sqrtf(var.z + LN_EPS);
    rs.w = 1.f / sqrtf(var.w + LN_EPS);
    float4 d = f4sub(z, m);
    float gc = gam[myc], ec = bet[myc];
    float4 h;
    h.x = fmaxf(fmaf(d.x * rs.x, gc, ec), 0.f);
    h.y = fmaxf(fmaf(d.y * rs.y, gc, ec), 0.f);
    h.z = fmaxf(fmaf(d.z * rs.z, gc, ec), 0.f);
    h.w = fmaxf(fmaf(d.w * rs.w, gc, ec), 0.f);
    outA[tid] = h;
    __syncthreads();                                   // sync 3
}

// ---------------- scan role: qtrunk + sampling ---------------------------
__device__ void scan_role(const Params &P, int bid, ScanS &S) {
    const int tid = threadIdx.x;
    const int ks = tid >> 7;
    const int cq = tid & 127;
    const int myc = 4 * cq + ks;
    const int row0 = bid * RPB;

    if (tid < VDIM) { S.VT[tid] = f4zero(); S.ord[tid] = P.top_order[tid]; }
    __syncthreads();
    if (tid < VDIM) {
        int nd = S.ord[tid];
        int mm = 0;
        for (int jj = 0; jj < tid; ++jj) mm |= P.pa_mask[nd * VDIM + S.ord[jj]];
        S.emptyb[tid] = (mm == 0);
        S.VPT[(tid & 3) * 32 + (tid >> 2)] = f4zero();   // V=0 -> V_pa=0
    }
    __syncthreads();

    // per-thread next-layer weight base pointers (include the ks*kc offset)
    constexpr int kc1 = VDIM / 4;   // 32
    constexpr int kcH = HDIM / 4;   // 128
    const float4 *w1p = (const float4 *)P.q_w1 + (size_t)(ks * kc1) * (HDIM / 4) + cq;
    const float4 *w2p = (const float4 *)P.q_w2 + (size_t)(ks * kcH) * (HDIM / 4) + cq;
    const float4 *w3p = (const float4 *)P.q_w3 + (size_t)(ks * kcH) * (HDIM / 4) + cq;

    float4 pf[4 * PFQ];
#pragma unroll
    for (int q = 0; q < PFQ; ++q) {        // prologue: L1 step-0 prefetch
        pf[4 * q + 0] = w1p[(size_t)(4 * q + 0) * (HDIM / 4)];
        pf[4 * q + 1] = w1p[(size_t)(4 * q + 1) * (HDIM / 4)];
        pf[4 * q + 2] = w1p[(size_t)(4 * q + 2) * (HDIM / 4)];
        pf[4 * q + 3] = w1p[(size_t)(4 * q + 3) * (HDIM / 4)];
    }

    for (int i = 0; i < VDIM; ++i) {
        const int node = S.ord[i];

        gemv_ln_scan<VDIM>(S.VPT, P.q_w1, P.q_b1, P.q_g1, P.q_be1, S.ATa, S,
                           tid, ks, cq, myc, pf, w2p);
        gemv_ln_scan<HDIM>(S.ATa, P.q_w2, P.q_b2, P.q_g2, P.q_be2, S.ATb, S,
                           tid, ks, cq, myc, pf, w3p);
        gemv_ln_scan<HDIM>(S.ATb, P.q_w3, P.q_b3, P.q_g3, P.q_be3, S.ATa, S,
                           tid, ks, cq, myc, pf, w1p);   // refills next step's L1

        // head: x[r] = sum_c h3[r][c] * q_W[node][c]  (broadcast to all)
        float wq = P.q_W[(size_t)node * HDIM + myc];
        float4 x4 = allreduce4_1s(f4scale(S.ATa[tid], wq), S.redH, tid);

        // merged sample + VPT(i+1) phase: ONE sync
        {
            const bool empty = (S.emptyb[i] != 0);
            const float qb = P.q_bias[node];
            const float mg = P.q_marg[node];
            float a0 = empty ? mg : x4.x + qb;
            float a1 = empty ? mg : x4.y + qb;
            float a2 = empty ? mg : x4.z + qb;
            float a3 = empty ? mg : x4.w + qb;
            float4 pv = make_float4(1.f / (1.f + expf(-a0)), 1.f / (1.f + expf(-a1)),
                                    1.f / (1.f + expf(-a2)), 1.f / (1.f + expf(-a3)));
            float4 uv = *(const float4 *)(P.u + (size_t)i * BATCH + row0);
            float4 newv = make_float4(uv.x < pv.x ? 1.f : -1.f,
                                      uv.y < pv.y ? 1.f : -1.f,
                                      uv.z < pv.z ? 1.f : -1.f,
                                      uv.w < pv.w ? 1.f : -1.f);
            if (tid < VDIM) {
                float mk = 0.f;
                if (i + 1 < VDIM) {
                    int nodeN = S.ord[i + 1];
                    mk = (float)P.pa_mask[nodeN * VDIM + tid];
                }
                float4 vk = S.VT[tid];
                if (tid == node) { vk = newv; S.VT[tid] = newv; }
                S.VPT[(tid & 3) * 32 + (tid >> 2)] = f4scale(vk, mk);
            }
            if (tid < RPB) {
                float pr = f4get(pv, tid);
                float vr = f4get(newv, tid);
                __hip_atomic_store(&P.vs[(size_t)i * BATCH + row0 + tid], vr,
                                   __ATOMIC_RELAXED, __HIP_MEMORY_SCOPE_AGENT);
                P.lp[(size_t)i * BATCH + row0 + tid] =
                    (vr > 0.f) ? logf(pr) : log1pf(-pr);
            }
            __syncthreads();
            if (tid == 0)
                __hip_atomic_store(P.wflag + bid, i + 1,
                                   __ATOMIC_RELEASE, __HIP_MEMORY_SCOPE_AGENT);
        }
    }

    // terminal score: V . J . V per row
    float4 inner = f4zero();
    if (tid < VDIM) {
#pragma unroll 4
        for (int ii = 0; ii < VDIM; ++ii)
            inner = f4fma(S.VT[ii], P.J[(size_t)ii * VDIM + tid], inner);
        float4 vc = S.VT[tid];
        inner = make_float4(inner.x * vc.x, inner.y * vc.y, inner.z * vc.z, inner.w * vc.w);
    }
    float4 sc4 = allreduce4_1s(inner, S.redH, tid);
    if (tid < RPB) P.score[row0 + tid] = f4get(sc4, tid);
    if (tid < VDIM) {
        float4 v = S.VT[tid];
        P.V_out[(size_t)(row0 + 0) * VDIM + tid] = v.x;
        P.V_out[(size_t)(row0 + 1) * VDIM + tid] = v.y;
        P.V_out[(size_t)(row0 + 2) * VDIM + tid] = v.z;
        P.V_out[(size_t)(row0 + 3) * VDIM + tid] = v.w;
    }
}

// ---------------- fnet layer, 512 threads, 32-row tile -------------------
template <int K>
__device__ __forceinline__ void flayer512(const float *__restrict__ in,
                                          const float *__restrict__ W,
                                          const float *__restrict__ bias,
                                          const float *__restrict__ gam,
                                          const float *__restrict__ bet,
                                          float *__restrict__ out,
                                          float4 *redA, float4 *redB, int tid) {
    const int rh = tid >> 7;
    const int cq = tid & 127;
    const float4 *Wv = (const float4 *)W + cq;
    float4 accA[4], accB[4];
#pragma unroll
    for (int j = 0; j < 4; ++j) { accA[j] = f4zero(); accB[j] = f4zero(); }
#pragma unroll 4
    for (int k = 0; k < K; ++k) {
        float4 w = Wv[(size_t)k * (HDIM / 4)];
        const float *ip = in + k * FROWS + 8 * rh;
        float4 vA = *(const float4 *)ip;
        float4 vB = *(const float4 *)(ip + 4);
        accA[0] = f4fma(vA, w.x, accA[0]); accB[0] = f4fma(vB, w.x, accB[0]);
        accA[1] = f4fma(vA, w.y, accA[1]); accB[1] = f4fma(vB, w.y, accB[1]);
        accA[2] = f4fma(vA, w.z, accA[2]); accB[2] = f4fma(vB, w.z, accB[2]);
        accA[3] = f4fma(vA, w.w, accA[3]); accB[3] = f4fma(vB, w.w, accB[3]);
    }
    float4 b4 = ((const float4 *)bias)[cq];
    float bb[4] = {b4.x, b4.y, b4.z, b4.w};
#pragma unroll
    for (int j = 0; j < 4; ++j) {
        accA[j].x += bb[j]; accA[j].y += bb[j]; accA[j].z += bb[j]; accA[j].w += bb[j];
        accB[j].x += bb[j]; accB[j].y += bb[j]; accB[j].z += bb[j]; accB[j].w += bb[j];
    }
    const float inv = 1.f / (float)HDIM;
    float4 sA = f4add(f4add(accA[0], accA[1]), f4add(accA[2], accA[3]));
    float4 sB = f4add(f4add(accB[0], accB[1]), f4add(accB[2], accB[3]));
    redpair(sA, sB, redA, redB, tid);
    float4 mA = f4scale(sA, inv), mB = f4scale(sB, inv);
    float4 dA[4], dB[4];
    float4 qA = f4zero(), qB = f4zero();
#pragma unroll
    for (int j = 0; j < 4; ++j) {
        dA[j] = f4sub(accA[j], mA);
        dB[j] = f4sub(accB[j], mB);
        qA.x += dA[j].x * dA[j].x; qA.y += dA[j].y * dA[j].y;
        qA.z += dA[j].z * dA[j].z; qA.w += dA[j].w * dA[j].w;
        qB.x += dB[j].x * dB[j].x; qB.y += dB[j].y * dB[j].y;
        qB.z += dB[j].z * dB[j].z; qB.w += dB[j].w * dB[j].w;
    }
    redpair(qA, qB, redA, redB, tid);
    float4 rsA, rsB;
    rsA.x = 1.f / sqrtf(qA.x * inv + LN_EPS); rsA.y = 1.f / sqrtf(qA.y * inv + LN_EPS);
    rsA.z = 1.f / sqrtf(qA.z * inv + LN_EPS); rsA.w = 1.f / sqrtf(qA.w * inv + LN_EPS);
    rsB.x = 1.f / sqrtf(qB.x * inv + LN_EPS); rsB.y = 1.f / sqrtf(qB.y * inv + LN_EPS);
    rsB.z = 1.f / sqrtf(qB.z * inv + LN_EPS); rsB.w = 1.f / sqrtf(qB.w * inv + LN_EPS);
    float4 g4 = ((const float4 *)gam)[cq];
    float4 e4 = ((const float4 *)bet)[cq];
    float gg[4] = {g4.x, g4.y, g4.z, g4.w};
    float ee[4] = {e4.x, e4.y, e4.z, e4.w};
#pragma unroll
    for (int j = 0; j < 4; ++j) {
        float4 hA, hB;
        hA.x = fmaxf(fmaf(dA[j].x * rsA.x, gg[j], ee[j]), 0.f);
        hA.y = fmaxf(fmaf(dA[j].y * rsA.y, gg[j], ee[j]), 0.f);
        hA.z = fmaxf(fmaf(dA[j].z * rsA.z, gg[j], ee[j]), 0.f);
        hA.w = fmaxf(fmaf(dA[j].w * rsA.w, gg[j], ee[j]), 0.f);
        hB.x = fmaxf(fmaf(dB[j].x * rsB.x, gg[j], ee[j]), 0.f);
        hB.y = fmaxf(fmaf(dB[j].y * rsB.y, gg[j], ee[j]), 0.f);
        hB.z = fmaxf(fmaf(dB[j].z * rsB.z, gg[j], ee[j]), 0.f);
        hB.w = fmaxf(fmaf(dB[j].w * rsB.w, gg[j], ee[j]), 0.f);
        float *op = out + (4 * cq + j) * FROWS + 8 * rh;
        *(float4 *)op = hA;
        *(float4 *)(op + 4) = hB;
    }
    __syncthreads();
}

// ---------------- worker role --------------------------------------------
__device__ void worker_role(const Params &P, int wid, WorkS &S) {
    const int tid = threadIdx.x;
    if (tid < VDIM) S.ord[tid] = P.top_order[tid];
    __syncthreads();
    if (tid < VDIM) S.invp[S.ord[tid]] = tid;
    __syncthreads();
    const int g = wid & (NGRP - 1);
    const int r0 = g * FROWS;

    for (int tile = wid; tile < VDIM * NGRP; tile += NWORK) {
        const int t = tile >> 4;
        if (t == VDIM - 1) continue;
        if (tid < SBPG) {
            const int need = t + 1;
            while (__hip_atomic_load(P.wflag + (SBPG * g + tid),
                                     __ATOMIC_RELAXED,
                                     __HIP_MEMORY_SCOPE_AGENT) < need)
                __builtin_amdgcn_s_sleep(4);
        }
        __syncthreads();
        for (int idx = tid; idx < VDIM * FROWS; idx += NT) {
            int k = idx >> 5, rr = idx & (FROWS - 1);
            int s = S.invp[k];
            S.Vt[idx] = (s <= t)
                ? __hip_atomic_load(&P.vs[(size_t)s * BATCH + r0 + rr],
                                    __ATOMIC_RELAXED, __HIP_MEMORY_SCOPE_AGENT)
                : 0.f;
        }
        __syncthreads();

        flayer512<VDIM>(S.Vt, P.f_w1, P.f_b1, P.f_g1, P.f_be1, S.A, S.redA, S.redB, tid);
        flayer512<HDIM>(S.A, P.f_w2, P.f_b2, P.f_g2, P.f_be2, S.A, S.redA, S.redB, tid);
        flayer512<HDIM>(S.A, P.f_w3, P.f_b3, P.f_g3, P.f_be3, S.A, S.redA, S.redB, tid);

        const int rh = tid >> 7, cq = tid & 127;
        float4 w4 = ((const float4 *)P.f_w4)[cq];
        float ww[4] = {w4.x, w4.y, w4.z, w4.w};
        float4 sA = f4zero(), sB = f4zero();
#pragma unroll
        for (int j = 0; j < 4; ++j) {
            const float *ap2 = S.A + (4 * cq + j) * FROWS + 8 * rh;
            float4 vA = *(const float4 *)ap2;
            float4 vB = *(const float4 *)(ap2 + 4);
            sA = f4fma(vA, ww[j], sA);
            sB = f4fma(vB, ww[j], sB);
        }
        redpair(sA, sB, S.redA, S.redB, tid);
        if (cq == 0) {
            float b4v = P.f_b4[0];
            float *dst = P.lf + (size_t)t * BATCH + r0 + 8 * rh;
            dst[0] = sA.x + b4v; dst[1] = sA.y + b4v;
            dst[2] = sA.z + b4v; dst[3] = sA.w + b4v;
            dst[4] = sB.x + b4v; dst[5] = sB.y + b4v;
            dst[6] = sB.z + b4v; dst[7] = sB.w + b4v;
        }
        __syncthreads();
    }
}

// XCD-partitioned roles (perf heuristic only; correctness mapping-free):
// scan -> XCDs 0-3 (q-weights resident), workers -> XCDs 4-7 (f-weights).
__global__ __launch_bounds__(NT) void gfn_main(Params P) {
    __shared__ SMem sm;
    const int xcd = blockIdx.x & 7;
    const int grp = blockIdx.x >> 3;
    if (xcd < 4) scan_role(P, grp * 4 + xcd, sm.s);
    else         worker_role(P, grp * 4 + (xcd - 4), sm.w);
}

// ---------------- loss ----------------
__global__ __launch_bounds__(NT) void gfn_loss(Params P) {
    __shared__ float H1[HDIM], H2[HDIM];
    __shared__ float red1[NWAVE];
    const int tid = threadIdx.x;
    const float inv = 1.f / (float)HDIM;

    float z = P.f_b1[tid];
    float m = block_reduce1(z, red1, tid) * inv;
    float d = z - m;
    float var = block_reduce1(d * d, red1, tid) * inv;
    float h = fmaxf(fmaf(d * (1.f / sqrtf(var + LN_EPS)), P.f_g1[tid], P.f_be1[tid]), 0.f);
    H1[tid] = h;
    __syncthreads();

    float acc = 0.f;
    for (int k = 0; k < HDIM; ++k) acc = fmaf(H1[k], P.f_w2[(size_t)k * HDIM + tid], acc);
    z = acc + P.f_b2[tid];
    m = block_reduce1(z, red1, tid) * inv;
    d = z - m;
    var = block_reduce1(d * d, red1, tid) * inv;
    h = fmaxf(fmaf(d * (1.f / sqrtf(var + LN_EPS)), P.f_g2[tid], P.f_be2[tid]), 0.f);
    H2[tid] = h;
    __syncthreads();

    acc = 0.f;
    for (int k = 0; k < HDIM; ++k) acc = fmaf(H2[k], P.f_w3[(size_t)k * HDIM + tid], acc);
    z = acc + P.f_b3[tid];
    m = block_reduce1(z, red1, tid) * inv;
    d = z - m;
    var = block_reduce1(d * d, red1, tid) * inv;
    h = fmaxf(fmaf(d * (1.f / sqrtf(var + LN_EPS)), P.f_g3[tid], P.f_be3[tid]), 0.f);
    float F0 = block_reduce1(h * P.f_w4[tid], red1, tid) + P.f_b4[0];

    const int b = tid;
    float lfp = F0;
    float s = 0.f;
    for (int t = 0; t < VDIM; ++t) {
        float lp = P.lp[(size_t)t * BATCH + b];
        float lfn = (t == VDIM - 1) ? P.score[b] : P.lf[(size_t)t * BATCH + b];
        float dd = lfp + lp - lfn;
        s = fmaf(dd, dd, s);
        lfp = lfn;
    }
    s *= (1.f / (float)VDIM);
    float total = block_reduce1(s, red1, tid) * (1.f / (float)BATCH);
    if (tid == 0) P.loss[0] = total;
}

extern "C" void kernel_launch(void *const *d_in, const int *in_sizes, int n_in,
                              void *d_out, int out_size, void *d_ws, size_t ws_size,
                              hipStream_t stream) {
    Params P;
    P.u     = (const float *)d_in[0];
    P.q_w1  = (const float *)d_in[1];
    P.q_b1  = (const float *)d_in[2];
    P.q_g1  = (const float *)d_in[3];
    P.q_be1 = (const float *)d_in[4];
    P.q_w2  = (const float *)d_in[5];
    P.q_b2  = (const float *)d_in[6];
    P.q_g2  = (const float *)d_in[7];
    P.q_be2 = (const float *)d_in[8];
    P.q_w3  = (const float *)d_in[9];
    P.q_b3  = (const float *)d_in[10];
    P.q_g3  = (const float *)d_in[11];
    P.q_be3 = (const float *)d_in[12];
    P.q_W   = (const float *)d_in[13];
    P.q_bias= (const float *)d_in[14];
    P.q_marg= (const float *)d_in[15];
    P.f_w1  = (const float *)d_in[16];
    P.f_b1  = (const float *)d_in[17];
    P.f_g1  = (const float *)d_in[18];
    P.f_be1 = (const float *)d_in[19];
    P.f_w2  = (const float *)d_in[20];
    P.f_b2  = (const float *)d_in[21];
    P.f_g2  = (const float *)d_in[22];
    P.f_be2 = (const float *)d_in[23];
    P.f_w3  = (const float *)d_in[24];
    P.f_b3  = (const float *)d_in[25];
    P.f_g3  = (const float *)d_in[26];
    P.f_be3 = (const float *)d_in[27];
    P.f_w4  = (const float *)d_in[28];
    P.f_b4  = (const float *)d_in[29];
    P.J     = (const float *)d_in[30];
    P.top_order = (const int *)d_in[31];
    P.pa_mask   = (const int *)d_in[32];

    float *ws = (float *)d_ws;
    P.V_out = (float *)d_out;
    P.loss  = (float *)d_out + (size_t)BATCH * VDIM;
    P.lp    = ws;                                       // [128][512]
    P.lf    = ws + (size_t)VDIM * BATCH;                // [128][512]
    P.score = ws + 2 * (size_t)VDIM * BATCH;            // [512]
    P.vs    = ws + 2 * (size_t)VDIM * BATCH + BATCH;    // [128][512]
    P.wflag = (int *)(ws + 3 * (size_t)VDIM * BATCH + BATCH);  // [128]

    hipMemsetAsync(P.wflag, 0, NBLK * sizeof(int), stream);
    gfn_main<<<dim3(NBLK + NWORK), dim3(NT), 0, stream>>>(P);
    gfn_loss<<<dim3(1), dim3(NT), 0, stream>>>(P);
}

// Round 14
// 3824.166 us; speedup vs baseline: 1.6770x; 1.6770x over previous
//
#include <hip/hip_runtime.h>
#include <hip/hip_bf16.h>
#include <math.h>

#define VDIM 128
#define HDIM 512
#define BATCH 512
#define RPB 4                  // batch rows per scan block
#define NBLK (BATCH / RPB)     // 128 scan blocks
#define NWORK 128              // persistent fnet worker blocks
#define NT 512
#define NWAVE 8
#define LN_EPS 1e-5f
#define FROWS 32               // fnet rows per tile
#define NGRP 16                // worker row groups (32 rows)
#define SBPG 8                 // scan blocks per worker row group

// ---------- float4 helpers ----------
__device__ __forceinline__ float4 f4zero() { return make_float4(0.f, 0.f, 0.f, 0.f); }
__device__ __forceinline__ float4 f4add(float4 a, float4 b) {
    return make_float4(a.x + b.x, a.y + b.y, a.z + b.z, a.w + b.w);
}
__device__ __forceinline__ float4 f4fma(float4 a, float s, float4 c) {
    return make_float4(fmaf(a.x, s, c.x), fmaf(a.y, s, c.y),
                       fmaf(a.z, s, c.z), fmaf(a.w, s, c.w));
}
__device__ __forceinline__ float4 f4scale(float4 a, float s) {
    return make_float4(a.x * s, a.y * s, a.z * s, a.w * s);
}
__device__ __forceinline__ float4 f4sub(float4 a, float4 b) {
    return make_float4(a.x - b.x, a.y - b.y, a.z - b.z, a.w - b.w);
}
__device__ __forceinline__ float f4get(float4 v, int r) {
    return r == 0 ? v.x : r == 1 ? v.y : r == 2 ? v.z : v.w;
}

struct Params {
    const float *u;
    const float *q_w1, *q_b1, *q_g1, *q_be1;
    const float *q_w2, *q_b2, *q_g2, *q_be2;
    const float *q_w3, *q_b3, *q_g3, *q_be3;
    const float *q_W, *q_bias, *q_marg;
    const float *f_w1, *f_b1, *f_g1, *f_be1;
    const float *f_w2, *f_b2, *f_g2, *f_be2;
    const float *f_w3, *f_b3, *f_g3, *f_be3;
    const float *f_w4, *f_b4, *J;
    const int *top_order, *pa_mask;
    int *wflag;
    float *V_out, *lp, *lf, *score, *vs, *loss;
};

// ---------------- shared-memory roles (union -> 83.4KB -> 1 block/CU) ----
struct ScanS {
    float4 VT[VDIM];           // V^T: [col] -> 4 rows
    float4 VPT[VDIM];          // permuted layer-1 input
    float4 ATa[HDIM];          // permuted activations (st(c)=(c&3)*128+(c>>2))
    float4 ATb[HDIM];
    float4 part[4][4][128];    // [j][ks][cb]  32KB
    float4 redA[NWAVE], redB[NWAVE];
};
struct WorkS {
    float Vt[VDIM * FROWS];    // 16KB [k][32]
    float A[HDIM * FROWS];     // 64KB [c][32]
    int ord[VDIM], invp[VDIM];
    float4 redA[NWAVE], redB[NWAVE];
};
union SMem { ScanS s; WorkS w; };

// ---- block-wide f4 allreduce, ONE sync (caller rotates redA/redB) ------
__device__ __forceinline__ float4 allreduce4_1s(float4 v, float4 *red, int tid) {
#pragma unroll
    for (int off = 1; off < 64; off <<= 1) {
        v.x += __shfl_xor(v.x, off, 64);
        v.y += __shfl_xor(v.y, off, 64);
        v.z += __shfl_xor(v.z, off, 64);
        v.w += __shfl_xor(v.w, off, 64);
    }
    if ((tid & 63) == 0) red[tid >> 6] = v;
    __syncthreads();
    float4 s = red[0];
#pragma unroll
    for (int w = 1; w < NWAVE; ++w) s = f4add(s, red[w]);
    return s;   // NO trailing sync: next red-write is >=1 sync away by construction
}

__device__ __forceinline__ float block_reduce1(float v, float *red, int tid) {
#pragma unroll
    for (int off = 1; off < 64; off <<= 1) v += __shfl_xor(v, off, 64);
    if ((tid & 63) == 0) red[tid >> 6] = v;
    __syncthreads();
    float s = 0.f;
#pragma unroll
    for (int w = 0; w < NWAVE; ++w) s += red[w];
    __syncthreads();
    return s;
}

__device__ __forceinline__ void redpair(float4 &a, float4 &b,
                                        float4 *redA, float4 *redB, int tid) {
#pragma unroll
    for (int off = 1; off < 64; off <<= 1) {
        a.x += __shfl_xor(a.x, off, 64); a.y += __shfl_xor(a.y, off, 64);
        a.z += __shfl_xor(a.z, off, 64); a.w += __shfl_xor(a.w, off, 64);
        b.x += __shfl_xor(b.x, off, 64); b.y += __shfl_xor(b.y, off, 64);
        b.z += __shfl_xor(b.z, off, 64); b.w += __shfl_xor(b.w, off, 64);
    }
    int w = tid >> 6;
    if ((tid & 63) == 0) { redA[w] = a; redB[w] = b; }
    __syncthreads();
    int p = w ^ 1;
    a = f4add(redA[w], redA[p]);
    b = f4add(redB[w], redB[p]);
    __syncthreads();
}

// ---------------- scan GEMV+LN (4-way K-split, permuted activations) ----
template <int K>
__device__ __forceinline__ void gemv_ln_scan(const float4 *__restrict__ inA,
                                             const float *__restrict__ W,
                                             const float *__restrict__ bias,
                                             const float *__restrict__ gam,
                                             const float *__restrict__ bet,
                                             float4 *__restrict__ outA,
                                             ScanS &S, int tid, int ks, int cq,
                                             int myc) {
    constexpr int kc = K / 4;      // rows per ks-chunk
    constexpr int q4 = kc / 4;
    constexpr int seg = K / 4;     // permuted segment stride
    const float4 *Wp = (const float4 *)W + (size_t)(ks * kc) * (HDIM / 4) + cq;
    const float4 *ap = inA + ks * q4;
    float4 acc0 = f4zero(), acc1 = f4zero(), acc2 = f4zero(), acc3 = f4zero();
#pragma unroll 4
    for (int q = 0; q < q4; ++q) {
        float4 a0 = ap[q];                 // LDS b128 broadcast (k = ks*kc+4q+0)
        float4 a1 = ap[q + seg];           // k = ..+1
        float4 a2 = ap[q + 2 * seg];       // k = ..+2
        float4 a3 = ap[q + 3 * seg];       // k = ..+3
        float4 w0 = Wp[(size_t)(4 * q + 0) * (HDIM / 4)];   // 1KB/wave coalesced
        float4 w1 = Wp[(size_t)(4 * q + 1) * (HDIM / 4)];
        float4 w2 = Wp[(size_t)(4 * q + 2) * (HDIM / 4)];
        float4 w3 = Wp[(size_t)(4 * q + 3) * (HDIM / 4)];
        acc0 = f4fma(a0, w0.x, acc0); acc1 = f4fma(a0, w0.y, acc1);
        acc2 = f4fma(a0, w0.z, acc2); acc3 = f4fma(a0, w0.w, acc3);
        acc0 = f4fma(a1, w1.x, acc0); acc1 = f4fma(a1, w1.y, acc1);
        acc2 = f4fma(a1, w1.z, acc2); acc3 = f4fma(a1, w1.w, acc3);
        acc0 = f4fma(a2, w2.x, acc0); acc1 = f4fma(a2, w2.y, acc1);
        acc2 = f4fma(a2, w2.z, acc2); acc3 = f4fma(a2, w2.w, acc3);
        acc0 = f4fma(a3, w3.x, acc0); acc1 = f4fma(a3, w3.y, acc1);
        acc2 = f4fma(a3, w3.z, acc2); acc3 = f4fma(a3, w3.w, acc3);
    }
    // conflict-free partial writes (lane stride 16B per j)
    S.part[0][ks][cq] = acc0;
    S.part[1][ks][cq] = acc1;
    S.part[2][ks][cq] = acc2;
    S.part[3][ks][cq] = acc3;
    __syncthreads();
    // combine (conflict-free reads: per 2-wave group j fixed, cb contiguous)
    const int j = ks, cb = cq;     // same decomposition of tid
    float4 acc = f4add(f4add(S.part[j][0][cb], S.part[j][1][cb]),
                       f4add(S.part[j][2][cb], S.part[j][3][cb]));
    float bc = bias[myc];
    acc.x += bc; acc.y += bc; acc.z += bc; acc.w += bc;
    // two-pass LN over 512 columns
    const float inv = 1.f / (float)HDIM;
    float4 m4 = f4scale(allreduce4_1s(acc, S.redA, tid), inv);
    float4 d = f4sub(acc, m4);
    float4 sq = make_float4(d.x * d.x, d.y * d.y, d.z * d.z, d.w * d.w);
    float4 var = f4scale(allreduce4_1s(sq, S.redB, tid), inv);
    float4 rs;
    rs.x = 1.f / sqrtf(var.x + LN_EPS);
    rs.y = 1.f / sqrtf(var.y + LN_EPS);
    rs.z = 1.f / sqrtf(var.z + LN_EPS);
    rs.w = 1.f / sqrtf(var.w + LN_EPS);
    float gc = gam[myc], ec = bet[myc];
    float4 h;
    h.x = fmaxf(fmaf(d.x * rs.x, gc, ec), 0.f);
    h.y = fmaxf(fmaf(d.y * rs.y, gc, ec), 0.f);
    h.z = fmaxf(fmaf(d.z * rs.z, gc, ec), 0.f);
    h.w = fmaxf(fmaf(d.w * rs.w, gc, ec), 0.f);
    outA[tid] = h;                 // contiguous write = st(myc)
    __syncthreads();
}

// ---------------- scan role: qtrunk + sampling, publishes vs + flags ----
__device__ void scan_role(const Params &P, int bid, ScanS &S) {
    const int tid = threadIdx.x;
    const int ks = tid >> 7;
    const int cq = tid & 127;
    const int myc = 4 * cq + ks;
    const int row0 = bid * RPB;

    if (tid < VDIM) S.VT[tid] = f4zero();
    __syncthreads();

    for (int i = 0; i < VDIM; ++i) {
        const int node = P.top_order[i];

        float4 apv = f4zero();
        if (tid < VDIM) {
            float mk = (float)P.pa_mask[node * VDIM + tid];
            float4 vp = f4scale(S.VT[tid], mk);
            S.VPT[(tid & 3) * 32 + (tid >> 2)] = vp;   // permuted store
            apv = make_float4(fabsf(vp.x), fabsf(vp.y), fabsf(vp.z), fabsf(vp.w));
        }
        float4 asum = allreduce4_1s(apv, S.redB, tid);  // sync publishes VPT

        gemv_ln_scan<VDIM>(S.VPT, P.q_w1, P.q_b1, P.q_g1, P.q_be1, S.ATa, S, tid, ks, cq, myc);
        gemv_ln_scan<HDIM>(S.ATa, P.q_w2, P.q_b2, P.q_g2, P.q_be2, S.ATb, S, tid, ks, cq, myc);
        gemv_ln_scan<HDIM>(S.ATb, P.q_w3, P.q_b3, P.q_g3, P.q_be3, S.ATa, S, tid, ks, cq, myc);

        // head: x[r] = sum_c h3[r][c] * q_W[node][c]
        float wq = P.q_W[(size_t)node * HDIM + myc];
        float4 x4 = allreduce4_1s(f4scale(S.ATa[tid], wq), S.redA, tid);

        if (tid < RPB) {
            const int r = tid;
            float asr = f4get(asum, r);
            float xr = f4get(x4, r) + P.q_bias[node];
            float arg = (asr == 0.f) ? P.q_marg[node] : xr;
            float p = 1.f / (1.f + expf(-arg));
            float uv = P.u[i * BATCH + row0 + r];
            bool samp = uv < p;
            float v = samp ? 1.f : -1.f;
            ((float *)&S.VT[node])[r] = v;
            // publish at agent coherence point (no stale-L2 read possible)
            __hip_atomic_store(&P.vs[(size_t)i * BATCH + row0 + r], v,
                               __ATOMIC_RELAXED, __HIP_MEMORY_SCOPE_AGENT);
            P.lp[(size_t)i * BATCH + row0 + r] = samp ? logf(p) : log1pf(-p);
        }
        __syncthreads();
        if (tid == 0) {
            // release: orders the vs stores before the flag update
            __hip_atomic_store(P.wflag + bid, i + 1,
                               __ATOMIC_RELEASE, __HIP_MEMORY_SCOPE_AGENT);
        }
    }

    // terminal score: V . J . V per row
    float4 inner = f4zero();
    if (tid < VDIM) {
#pragma unroll 4
        for (int ii = 0; ii < VDIM; ++ii)
            inner = f4fma(S.VT[ii], P.J[(size_t)ii * VDIM + tid], inner);
        float4 vc = S.VT[tid];
        inner = make_float4(inner.x * vc.x, inner.y * vc.y, inner.z * vc.z, inner.w * vc.w);
    }
    float4 sc4 = allreduce4_1s(inner, S.redA, tid);
    if (tid < RPB) P.score[row0 + tid] = f4get(sc4, tid);
    if (tid < VDIM) {
        float4 v = S.VT[tid];
        P.V_out[(size_t)(row0 + 0) * VDIM + tid] = v.x;
        P.V_out[(size_t)(row0 + 1) * VDIM + tid] = v.y;
        P.V_out[(size_t)(row0 + 2) * VDIM + tid] = v.z;
        P.V_out[(size_t)(row0 + 3) * VDIM + tid] = v.w;
    }
}

// ---------------- fnet layer, 512 threads, 32-row tile ------------------
template <int K>
__device__ __forceinline__ void flayer512(const float *__restrict__ in,
                                          const float *__restrict__ W,
                                          const float *__restrict__ bias,
                                          const float *__restrict__ gam,
                                          const float *__restrict__ bet,
                                          float *__restrict__ out,
                                          float4 *redA, float4 *redB, int tid) {
    const int rh = tid >> 7;       // row octet: rows 8rh..8rh+7
    const int cq = tid & 127;      // col f4 block
    const float4 *Wv = (const float4 *)W + cq;
    float4 accA[4], accB[4];
#pragma unroll
    for (int j = 0; j < 4; ++j) { accA[j] = f4zero(); accB[j] = f4zero(); }
#pragma unroll 4
    for (int k = 0; k < K; ++k) {
        float4 w = Wv[(size_t)k * (HDIM / 4)];
        const float *ip = in + k * FROWS + 8 * rh;
        float4 vA = *(const float4 *)ip;
        float4 vB = *(const float4 *)(ip + 4);
        accA[0] = f4fma(vA, w.x, accA[0]); accB[0] = f4fma(vB, w.x, accB[0]);
        accA[1] = f4fma(vA, w.y, accA[1]); accB[1] = f4fma(vB, w.y, accB[1]);
        accA[2] = f4fma(vA, w.z, accA[2]); accB[2] = f4fma(vB, w.z, accB[2]);
        accA[3] = f4fma(vA, w.w, accA[3]); accB[3] = f4fma(vB, w.w, accB[3]);
    }
    float4 b4 = ((const float4 *)bias)[cq];
    float bb[4] = {b4.x, b4.y, b4.z, b4.w};
#pragma unroll
    for (int j = 0; j < 4; ++j) {
        accA[j].x += bb[j]; accA[j].y += bb[j]; accA[j].z += bb[j]; accA[j].w += bb[j];
        accB[j].x += bb[j]; accB[j].y += bb[j]; accB[j].z += bb[j]; accB[j].w += bb[j];
    }
    const float inv = 1.f / (float)HDIM;
    float4 sA = f4add(f4add(accA[0], accA[1]), f4add(accA[2], accA[3]));
    float4 sB = f4add(f4add(accB[0], accB[1]), f4add(accB[2], accB[3]));
    redpair(sA, sB, redA, redB, tid);
    float4 mA = f4scale(sA, inv), mB = f4scale(sB, inv);
    float4 dA[4], dB[4];
    float4 qA = f4zero(), qB = f4zero();
#pragma unroll
    for (int j = 0; j < 4; ++j) {
        dA[j] = f4sub(accA[j], mA);
        dB[j] = f4sub(accB[j], mB);
        qA.x += dA[j].x * dA[j].x; qA.y += dA[j].y * dA[j].y;
        qA.z += dA[j].z * dA[j].z; qA.w += dA[j].w * dA[j].w;
        qB.x += dB[j].x * dB[j].x; qB.y += dB[j].y * dB[j].y;
        qB.z += dB[j].z * dB[j].z; qB.w += dB[j].w * dB[j].w;
    }
    redpair(qA, qB, redA, redB, tid);
    float4 rsA, rsB;
    rsA.x = 1.f / sqrtf(qA.x * inv + LN_EPS); rsA.y = 1.f / sqrtf(qA.y * inv + LN_EPS);
    rsA.z = 1.f / sqrtf(qA.z * inv + LN_EPS); rsA.w = 1.f / sqrtf(qA.w * inv + LN_EPS);
    rsB.x = 1.f / sqrtf(qB.x * inv + LN_EPS); rsB.y = 1.f / sqrtf(qB.y * inv + LN_EPS);
    rsB.z = 1.f / sqrtf(qB.z * inv + LN_EPS); rsB.w = 1.f / sqrtf(qB.w * inv + LN_EPS);
    float4 g4 = ((const float4 *)gam)[cq];
    float4 e4 = ((const float4 *)bet)[cq];
    float gg[4] = {g4.x, g4.y, g4.z, g4.w};
    float ee[4] = {e4.x, e4.y, e4.z, e4.w};
#pragma unroll
    for (int j = 0; j < 4; ++j) {
        float4 hA, hB;
        hA.x = fmaxf(fmaf(dA[j].x * rsA.x, gg[j], ee[j]), 0.f);
        hA.y = fmaxf(fmaf(dA[j].y * rsA.y, gg[j], ee[j]), 0.f);
        hA.z = fmaxf(fmaf(dA[j].z * rsA.z, gg[j], ee[j]), 0.f);
        hA.w = fmaxf(fmaf(dA[j].w * rsA.w, gg[j], ee[j]), 0.f);
        hB.x = fmaxf(fmaf(dB[j].x * rsB.x, gg[j], ee[j]), 0.f);
        hB.y = fmaxf(fmaf(dB[j].y * rsB.y, gg[j], ee[j]), 0.f);
        hB.z = fmaxf(fmaf(dB[j].z * rsB.z, gg[j], ee[j]), 0.f);
        hB.w = fmaxf(fmaf(dB[j].w * rsB.w, gg[j], ee[j]), 0.f);
        float *op = out + (4 * cq + j) * FROWS + 8 * rh;
        *(float4 *)op = hA;
        *(float4 *)(op + 4) = hB;
    }
    __syncthreads();
}

// ---------------- worker role: polls scan progress, evaluates fnet ------
__device__ void worker_role(const Params &P, int wid, WorkS &S) {
    const int tid = threadIdx.x;
    if (tid < VDIM) S.ord[tid] = P.top_order[tid];
    __syncthreads();
    if (tid < VDIM) S.invp[S.ord[tid]] = tid;
    __syncthreads();
    const int g = wid & (NGRP - 1);        // fixed row group
    const int r0 = g * FROWS;

    for (int tile = wid; tile < VDIM * NGRP; tile += NWORK) {
        const int t = tile >> 4;           // step
        if (t == VDIM - 1) continue;       // lf[127] replaced by score in loss
        if (tid < SBPG) {
            const int need = t + 1;
            // relaxed poll at coherence point (8 lanes, one flag each)
            while (__hip_atomic_load(P.wflag + (SBPG * g + tid),
                                     __ATOMIC_RELAXED,
                                     __HIP_MEMORY_SCOPE_AGENT) < need)
                __builtin_amdgcn_s_sleep(4);
        }
        __syncthreads();
        for (int idx = tid; idx < VDIM * FROWS; idx += NT) {
            int k = idx >> 5, rr = idx & (FROWS - 1);
            int s = S.invp[k];
            S.Vt[idx] = (s <= t)
                ? __hip_atomic_load(&P.vs[(size_t)s * BATCH + r0 + rr],
                                    __ATOMIC_RELAXED, __HIP_MEMORY_SCOPE_AGENT)
                : 0.f;
        }
        __syncthreads();

        flayer512<VDIM>(S.Vt, P.f_w1, P.f_b1, P.f_g1, P.f_be1, S.A, S.redA, S.redB, tid);
        flayer512<HDIM>(S.A, P.f_w2, P.f_b2, P.f_g2, P.f_be2, S.A, S.redA, S.redB, tid);
        flayer512<HDIM>(S.A, P.f_w3, P.f_b3, P.f_g3, P.f_be3, S.A, S.redA, S.redB, tid);

        const int rh = tid >> 7, cq = tid & 127;
        float4 w4 = ((const float4 *)P.f_w4)[cq];
        float ww[4] = {w4.x, w4.y, w4.z, w4.w};
        float4 sA = f4zero(), sB = f4zero();
#pragma unroll
        for (int j = 0; j < 4; ++j) {
            const float *ap2 = S.A + (4 * cq + j) * FROWS + 8 * rh;
            float4 vA = *(const float4 *)ap2;
            float4 vB = *(const float4 *)(ap2 + 4);
            sA = f4fma(vA, ww[j], sA);
            sB = f4fma(vB, ww[j], sB);
        }
        redpair(sA, sB, S.redA, S.redB, tid);
        if (cq == 0) {
            float b4v = P.f_b4[0];
            float *dst = P.lf + (size_t)t * BATCH + r0 + 8 * rh;
            dst[0] = sA.x + b4v; dst[1] = sA.y + b4v;
            dst[2] = sA.z + b4v; dst[3] = sA.w + b4v;
            dst[4] = sB.x + b4v; dst[5] = sB.y + b4v;
            dst[6] = sB.z + b4v; dst[7] = sB.w + b4v;
        }
        __syncthreads();
    }
}

// XCD-partitioned role assignment: blockIdx round-robins across the 8 XCDs
// (perf heuristic only). Scan blocks -> XCDs 0-3 (q-weights pinned in those
// L2s, 2.5MB each); workers -> XCDs 4-7 (f-weights, 2.25MB each). Both fit
// 4MB L2 -> no thrash. 1 block/CU (83.4KB LDS) => all 256 blocks co-resident
// whatever the real mapping is, so the flag protocol cannot deadlock.
__global__ __launch_bounds__(NT) void gfn_main(Params P) {
    __shared__ SMem sm;
    const int xcd = blockIdx.x & 7;
    const int grp = blockIdx.x >> 3;       // 0..31
    if (xcd < 4) scan_role(P, grp * 4 + xcd, sm.s);
    else         worker_role(P, grp * 4 + (xcd - 4), sm.w);
}

// ---------------- loss ----------------
__global__ __launch_bounds__(NT) void gfn_loss(Params P) {
    __shared__ float H1[HDIM], H2[HDIM];
    __shared__ float red1[NWAVE];
    const int tid = threadIdx.x;
    const float inv = 1.f / (float)HDIM;

    float z = P.f_b1[tid];
    float m = block_reduce1(z, red1, tid) * inv;
    float d = z - m;
    float var = block_reduce1(d * d, red1, tid) * inv;
    float h = fmaxf(fmaf(d * (1.f / sqrtf(var + LN_EPS)), P.f_g1[tid], P.f_be1[tid]), 0.f);
    H1[tid] = h;
    __syncthreads();

    float acc = 0.f;
    for (int k = 0; k < HDIM; ++k) acc = fmaf(H1[k], P.f_w2[(size_t)k * HDIM + tid], acc);
    z = acc + P.f_b2[tid];
    m = block_reduce1(z, red1, tid) * inv;
    d = z - m;
    var = block_reduce1(d * d, red1, tid) * inv;
    h = fmaxf(fmaf(d * (1.f / sqrtf(var + LN_EPS)), P.f_g2[tid], P.f_be2[tid]), 0.f);
    H2[tid] = h;
    __syncthreads();

    acc = 0.f;
    for (int k = 0; k < HDIM; ++k) acc = fmaf(H2[k], P.f_w3[(size_t)k * HDIM + tid], acc);
    z = acc + P.f_b3[tid];
    m = block_reduce1(z, red1, tid) * inv;
    d = z - m;
    var = block_reduce1(d * d, red1, tid) * inv;
    h = fmaxf(fmaf(d * (1.f / sqrtf(var + LN_EPS)), P.f_g3[tid], P.f_be3[tid]), 0.f);
    float F0 = block_reduce1(h * P.f_w4[tid], red1, tid) + P.f_b4[0];

    const int b = tid;
    float lfp = F0;
    float s = 0.f;
    for (int t = 0; t < VDIM; ++t) {
        float lp = P.lp[(size_t)t * BATCH + b];
        float lfn = (t == VDIM - 1) ? P.score[b] : P.lf[(size_t)t * BATCH + b];
        float dd = lfp + lp - lfn;
        s = fmaf(dd, dd, s);
        lfp = lfn;
    }
    s *= (1.f / (float)VDIM);
    float total = block_reduce1(s, red1, tid) * (1.f / (float)BATCH);
    if (tid == 0) P.loss[0] = total;
}

extern "C" void kernel_launch(void *const *d_in, const int *in_sizes, int n_in,
                              void *d_out, int out_size, void *d_ws, size_t ws_size,
                              hipStream_t stream) {
    Params P;
    P.u     = (const float *)d_in[0];
    P.q_w1  = (const float *)d_in[1];
    P.q_b1  = (const float *)d_in[2];
    P.q_g1  = (const float *)d_in[3];
    P.q_be1 = (const float *)d_in[4];
    P.q_w2  = (const float *)d_in[5];
    P.q_b2  = (const float *)d_in[6];
    P.q_g2  = (const float *)d_in[7];
    P.q_be2 = (const float *)d_in[8];
    P.q_w3  = (const float *)d_in[9];
    P.q_b3  = (const float *)d_in[10];
    P.q_g3  = (const float *)d_in[11];
    P.q_be3 = (const float *)d_in[12];
    P.q_W   = (const float *)d_in[13];
    P.q_bias= (const float *)d_in[14];
    P.q_marg= (const float *)d_in[15];
    P.f_w1  = (const float *)d_in[16];
    P.f_b1  = (const float *)d_in[17];
    P.f_g1  = (const float *)d_in[18];
    P.f_be1 = (const float *)d_in[19];
    P.f_w2  = (const float *)d_in[20];
    P.f_b2  = (const float *)d_in[21];
    P.f_g2  = (const float *)d_in[22];
    P.f_be2 = (const float *)d_in[23];
    P.f_w3  = (const float *)d_in[24];
    P.f_b3  = (const float *)d_in[25];
    P.f_g3  = (const float *)d_in[26];
    P.f_be3 = (const float *)d_in[27];
    P.f_w4  = (const float *)d_in[28];
    P.f_b4  = (const float *)d_in[29];
    P.J     = (const float *)d_in[30];
    P.top_order = (const int *)d_in[31];
    P.pa_mask   = (const int *)d_in[32];

    float *ws = (float *)d_ws;
    P.V_out = (float *)d_out;
    P.loss  = (float *)d_out + (size_t)BATCH * VDIM;
    P.lp    = ws;                                       // [128][512]
    P.lf    = ws + (size_t)VDIM * BATCH;                // [128][512]
    P.score = ws + 2 * (size_t)VDIM * BATCH;            // [512]
    P.vs    = ws + 2 * (size_t)VDIM * BATCH + BATCH;    // [128][512]
    P.wflag = (int *)(ws + 3 * (size_t)VDIM * BATCH + BATCH);  // [128]

    hipMemsetAsync(P.wflag, 0, NBLK * sizeof(int), stream);
    gfn_main<<<dim3(NBLK + NWORK), dim3(NT), 0, stream>>>(P);
    gfn_loss<<<dim3(1), dim3(NT), 0, stream>>>(P);
}